// Round 8
// baseline (311.705 us; speedup 1.0000x reference)
//
#include <hip/hip_runtime.h>

// LRU recurrence — substitution bisect: verified mono FRONT-END computes exact
// state snapshots x_{64c} (k_state, serial over T but no Y work), then k_main
// (2048 blocks, chunk-parallel) redoes each 64-step chunk from the bitwise-mono
// snapshot and does the Y-GEMM. k_y0 emits Y[0]. Fallback: full verified mono.

constexpr int NY  = 64;
constexpr int NU  = 32;
constexpr int NH  = 512;
constexpr int NH2 = 256;
constexpr int BB  = 256;
constexpr int KK  = 16;

// mono / k_state pitches (round-4/5 verified)
constexpr int MUSP = 40;
constexpr int MXSP = 544;
constexpr int MBUP = 516;
constexpr int MPSP = 20;
// k_main pitches (round-6/7)
constexpr int USP = 40;
constexpr int XSP = 520;
constexpr int BUP = 513;
constexpr int PSP = 74;

typedef __attribute__((ext_vector_type(4))) short sh4;
typedef __attribute__((ext_vector_type(8))) short sh8;
typedef __attribute__((ext_vector_type(4))) float f32x4;

#define MFMA16(a, b, c) __builtin_amdgcn_mfma_f32_16x16x32_bf16((a), (b), (c), 0, 0, 0)

static __device__ __forceinline__ unsigned short bfh(float x) {
    return (unsigned short)(__float_as_uint(x) >> 16);
}
static __device__ __forceinline__ float bf2f(unsigned short h) {
    return __uint_as_float(((unsigned)h) << 16);
}
static __device__ __forceinline__ void cvt4(const float4 f, sh4& vh, sh4& vl) {
    const float e[4] = { f.x, f.y, f.z, f.w };
#pragma unroll
    for (int j = 0; j < 4; ++j) {
        const unsigned short h = bfh(e[j]);
        vh[j] = (short)h;
        vl[j] = (short)bfh(e[j] - bf2f(h));
    }
}
static __device__ __forceinline__ unsigned cvtpk(float a, float b) {
    unsigned r;
    asm("v_cvt_pk_bf16_f32 %0, %1, %2" : "=v"(r) : "v"(a), "v"(b));
    return r;
}
static __device__ __forceinline__ void xs_store(unsigned* xh, unsigned* xl, int idx,
                                                float xr, float xi) {
    const unsigned hp = cvtpk(xr, xi);
    const float rr = __uint_as_float(hp << 16);
    const float ri = __uint_as_float(hp & 0xffff0000u);
    xh[idx] = hp;
    xl[idx] = cvtpk(xr - rr, xi - ri);
}

// =============== k_state: mono front-end + snapshots (VERIFIED structure) ===============
__global__ __launch_bounds__(512, 2)
void k_state(const float* __restrict__ y0, const float* __restrict__ U,
             const float* __restrict__ lmr, const float* __restrict__ lmi,
             const float* __restrict__ Bmat, const float* __restrict__ Wy2x,
             const float* __restrict__ by2x, float* __restrict__ wsX)
{
    const int b = blockIdx.x, tid = threadIdx.x;
    const int w = tid >> 6, l = tid & 63, lr16 = l & 15, lg = l >> 4;

    __shared__ unsigned short us_h[2][64][MUSP], us_l[2][64][MUSP];
    __shared__ float bu[KK][MBUP];
    __shared__ float y0s[NY];

    sh8 fbh[8], fbl[8];
    float lamr = 0.f, lami = 0.f, xr = 0.f, xi = 0.f;
    if (tid < NH2) {
#pragma unroll
        for (int q = 0; q < 8; ++q) {
            sh8 vh, vl;
#pragma unroll
            for (int h2 = 0; h2 < 2; ++h2) {
                const int hrow = (w << 7) + (q << 4) + lr16;
                const int u0   = (h2 << 4) + (lg << 2);
                const float4 f4 = *reinterpret_cast<const float4*>(&Bmat[hrow * NU + u0]);
                sh4 th, tl;
                cvt4(f4, th, tl);
#pragma unroll
                for (int j = 0; j < 4; ++j) { vh[h2 * 4 + j] = th[j]; vl[h2 * 4 + j] = tl[j]; }
            }
            fbh[q] = vh;
            fbl[q] = vl;
        }
        lamr = lmr[tid];
        lami = lmi[tid];
    }

    const float4* Ug = reinterpret_cast<const float4*>(U);
    {
        const int i = tid, t = i >> 3, g = i & 7;
        const float4 f = Ug[((t * BB + b) << 3) + g];
        const int pos = (g < 4) ? (g << 3) : (((g - 4) << 3) + 4);
        sh4 vh, vl;
        cvt4(f, vh, vl);
        *reinterpret_cast<sh4*>(&us_h[0][t][pos]) = vh;
        *reinterpret_cast<sh4*>(&us_l[0][t][pos]) = vl;
    }
    if (tid < NY) y0s[tid] = y0[b * NY + tid];
    __syncthreads();

    if (tid < NH2) {
        const float* wr = &Wy2x[tid * NY];
        const float* wi = &Wy2x[(NH2 + tid) * NY];
        float a0 = 0, a1 = 0, a2 = 0, a3 = 0;
        float c0 = 0, c1 = 0, c2 = 0, c3 = 0;
#pragma unroll
        for (int y = 0; y < NY; y += 4) {
            a0 += wr[y + 0] * y0s[y + 0];
            a1 += wr[y + 1] * y0s[y + 1];
            a2 += wr[y + 2] * y0s[y + 2];
            a3 += wr[y + 3] * y0s[y + 3];
            c0 += wi[y + 0] * y0s[y + 0];
            c1 += wi[y + 1] * y0s[y + 1];
            c2 += wi[y + 2] * y0s[y + 2];
            c3 += wi[y + 3] * y0s[y + 3];
        }
        xr = by2x[tid]       + (a0 + a1) + (a2 + a3);
        xi = by2x[NH2 + tid] + (c0 + c1) + (c2 + c3);
    }

    float4 pf0, pf1;
    for (int st = 0; st < 32; ++st) {
        // snapshot: state at top of iteration st is x_{16*st}
        if (tid < NH2 && (st & 3) == 0) {
            wsX[(b * 8 + (st >> 2)) * 512 + tid]       = xr;
            wsX[(b * 8 + (st >> 2)) * 512 + 256 + tid] = xi;
        }
        if (tid < NH2) {   // Bu-MFMA for timesteps 16st..16st+15 (verbatim mono)
            const int su = (st >> 2) & 1, t0 = (st & 3) << 4;
            const sh8 auh = *reinterpret_cast<const sh8*>(&us_h[su][t0 + lr16][lg << 3]);
            const sh8 aul = *reinterpret_cast<const sh8*>(&us_l[su][t0 + lr16][lg << 3]);
#pragma unroll
            for (int q = 0; q < 8; ++q) {
                f32x4 acc = (f32x4){0.f, 0.f, 0.f, 0.f};
                acc = MFMA16(auh, fbh[q], acc);
                acc = MFMA16(aul, fbh[q], acc);
                acc = MFMA16(auh, fbl[q], acc);
                const int h = (w << 7) + (q << 4) + lr16;
#pragma unroll
                for (int r = 0; r < 4; ++r) bu[(lg << 2) + r][h] = acc[r];
            }
        } else {
            const int cc = st >> 2;
            if ((st & 3) == 0 && cc < 7) {
                const int i0 = tid - NH2, i1 = tid;
                pf0 = Ug[(((((cc + 1) << 6) + (i0 >> 3)) * BB + b) << 3) + (i0 & 7)];
                pf1 = Ug[(((((cc + 1) << 6) + (i1 >> 3)) * BB + b) << 3) + (i1 & 7)];
            }
        }
        __syncthreads();
        if (tid < NH2) {   // fp32 recurrence (verbatim mono, no xs publish)
#pragma unroll
            for (int k = 0; k < KK; ++k) {
                const float bur = bu[k][tid];
                const float bui = bu[k][256 + tid];
                const float nr = lamr * xr - lami * xi + bur;
                const float ni = lami * xr + lamr * xi + bui;
                xr = nr;
                xi = ni;
            }
        } else if ((st & 3) == 1 && (st >> 2) < 7) {
            const int ns = ((st >> 2) + 1) & 1;
#pragma unroll
            for (int v = 0; v < 2; ++v) {
                const float4 f = v ? pf1 : pf0;
                const int i = v ? tid : (tid - NH2);
                const int t = i >> 3, g = i & 7;
                const int pos = (g < 4) ? (g << 3) : (((g - 4) << 3) + 4);
                sh4 vh, vl;
                cvt4(f, vh, vl);
                *reinterpret_cast<sh4*>(&us_h[ns][t][pos]) = vh;
                *reinterpret_cast<sh4*>(&us_l[ns][t][pos]) = vl;
            }
        }
        __syncthreads();
    }
}

// =============== k_y0: Y[0] from snapshot slot 0 ===============
__global__ __launch_bounds__(256)
void k_y0(const float* __restrict__ Wx2y, const float* __restrict__ bx2y,
          const float* __restrict__ wsX, float* __restrict__ Y)
{
    const int b = blockIdx.x, tid = threadIdx.x;
    __shared__ float x0s[NH];
    __shared__ float ps0[4][80];

    x0s[tid]       = wsX[(b * 8) * 512 + tid];
    x0s[256 + tid] = wsX[(b * 8) * 512 + 256 + tid];
    __syncthreads();

    const int n = tid & 63, kq = tid >> 6;
    const float* Wn = Wx2y + n * NH + (kq << 7);
    const float* xq = x0s + (kq << 7);
    float a0 = 0, a1 = 0, a2 = 0, a3 = 0;
#pragma unroll
    for (int h = 0; h < 128; h += 4) {
        a0 += Wn[h + 0] * xq[h + 0];
        a1 += Wn[h + 1] * xq[h + 1];
        a2 += Wn[h + 2] * xq[h + 2];
        a3 += Wn[h + 3] * xq[h + 3];
    }
    ps0[kq][n] = (a0 + a1) + (a2 + a3);
    __syncthreads();
    if (tid < NY)
        Y[b * NY + tid] = ps0[0][tid] + ps0[1][tid] + ps0[2][tid] + ps0[3][tid] + bx2y[tid];
}

// =============== k_main: chunk-parallel pipeline (round-6/7 K3, float ws) ===============
__global__ __launch_bounds__(512, 4)
void k_main(const float* __restrict__ U,
            const float* __restrict__ lmr, const float* __restrict__ lmi,
            const float* __restrict__ Bmat, const float* __restrict__ Wx2y,
            const float* __restrict__ bx2y, const float* __restrict__ wsX,
            float* __restrict__ Y)
{
    const int bc = blockIdx.x;
    const int b = bc >> 3, c = bc & 7;
    const int tid = threadIdx.x;
    const int w = tid >> 6, l = tid & 63, lr16 = l & 15, lg = l >> 4;

    __shared__ unsigned short us_h[KK][USP], us_l[KK][USP];
    __shared__ unsigned short xs_h[KK][XSP], xs_l[KK][XSP];
    __shared__ float bu[KK][BUP];
    __shared__ float psy[2][KK][PSP];

    sh8 bbh[4], bbl[4];
#pragma unroll
    for (int q = 0; q < 4; ++q) {
        sh8 vh, vl;
#pragma unroll
        for (int h2 = 0; h2 < 2; ++h2) {
            const int hrow = (w << 6) + (q << 4) + lr16;
            const int u0   = (h2 << 4) + (lg << 2);
            const float4 f4 = *reinterpret_cast<const float4*>(&Bmat[hrow * NU + u0]);
            sh4 th, tl;
            cvt4(f4, th, tl);
#pragma unroll
            for (int j = 0; j < 4; ++j) { vh[h2 * 4 + j] = th[j]; vl[h2 * 4 + j] = tl[j]; }
        }
        bbh[q] = vh;
        bbl[q] = vl;
    }

    const int nt = w >> 1, kh = w & 1;
    sh8 whi[8], wlo[8];
    {
        const float* Wn = Wx2y + ((nt << 4) + lr16) * NH;
#pragma unroll
        for (int ks = 0; ks < 8; ++ks) {
            sh8 vh, vl;
#pragma unroll
            for (int h2 = 0; h2 < 2; ++h2) {
                const int k0 = (kh << 8) + (ks << 5) + (h2 << 4) + (lg << 2);
                const int p0 = k0 >> 1;
                const float e[4] = { Wn[p0], Wn[p0 + 256], Wn[p0 + 1], Wn[p0 + 257] };
#pragma unroll
                for (int j2 = 0; j2 < 4; ++j2) {
                    const unsigned short h = bfh(e[j2]);
                    vh[h2 * 4 + j2] = (short)h;
                    vl[h2 * 4 + j2] = (short)bfh(e[j2] - bf2f(h));
                }
            }
            whi[ks] = vh;
            wlo[ks] = vl;
        }
    }
    const float bias = bx2y[l];

    float lamr = 0.f, lami = 0.f, xr = 0.f, xi = 0.f;
    int xwrd = 0;
    if (tid < NH2) {
        lamr = lmr[tid];
        lami = lmi[tid];
        xr = wsX[(b * 8 + c) * 512 + tid];         // bitwise-mono snapshot x_{64c}
        xi = wsX[(b * 8 + c) * 512 + 256 + tid];
        const int q_ = tid & 15, blk = tid >> 4;
        xwrd = blk * 16 + ((q_ & 7) >> 1) * 4 + (q_ >> 3) * 2 + (q_ & 1);
    }

    const float4* Ug = reinterpret_cast<const float4*>(U);
    float4 pf;
    if (tid < 128) {
        const int tg = (c << 6) + (tid >> 3), g = tid & 7;
        pf = Ug[(tg * BB + b) * 8 + g];
    }

    for (int ss = 0; ss < 4; ++ss) {
        if (tid < 128) {
            const float4 cur = pf;
            if (ss < 3) {
                const int tg = (c << 6) + ((ss + 1) << 4) + (tid >> 3), g = tid & 7;
                pf = Ug[(tg * BB + b) * 8 + g];
            }
            const int t = tid >> 3, g = tid & 7;
            const int pos = (g < 4) ? (g << 3) : (((g - 4) << 3) + 4);
            sh4 vh, vl;
            cvt4(cur, vh, vl);
            *reinterpret_cast<sh4*>(&us_h[t][pos]) = vh;
            *reinterpret_cast<sh4*>(&us_l[t][pos]) = vl;
        }
        if (ss > 0) {
#pragma unroll
            for (int rr = 0; rr < 2; ++rr) {
                const int m = (w << 1) + rr;
                const float v = psy[0][m][18 * lg + lr16] + psy[1][m][18 * lg + lr16] + bias;
                const int s = (c << 6) + ((ss - 1) << 4) + m + 1;
                Y[(s * BB + b) * NY + l] = v;
            }
        }
        __syncthreads();
        {
            const sh8 auh = *reinterpret_cast<const sh8*>(&us_h[lr16][lg << 3]);
            const sh8 aul = *reinterpret_cast<const sh8*>(&us_l[lr16][lg << 3]);
#pragma unroll
            for (int q = 0; q < 4; ++q) {
                f32x4 acc = (f32x4){0.f, 0.f, 0.f, 0.f};
                acc = MFMA16(auh, bbh[q], acc);
                acc = MFMA16(aul, bbh[q], acc);
                acc = MFMA16(auh, bbl[q], acc);
                const int h = (w << 6) + (q << 4) + lr16;
#pragma unroll
                for (int r = 0; r < 4; ++r) bu[(lg << 2) + r][h] = acc[r];
            }
        }
        __syncthreads();
        if (tid < NH2) {
            unsigned* xh = reinterpret_cast<unsigned*>(&xs_h[0][0]);
            unsigned* xl = reinterpret_cast<unsigned*>(&xs_l[0][0]);
#pragma unroll
            for (int k = 0; k < KK; ++k) {
                const float bur = bu[k][tid];
                const float bui = bu[k][256 + tid];
                const float nr = lamr * xr - lami * xi + bur;
                const float ni = lami * xr + lamr * xi + bui;
                xr = nr;
                xi = ni;
                xs_store(xh, xl, k * (XSP / 2) + xwrd, xr, xi);
            }
        }
        __syncthreads();
        {
            f32x4 aa = (f32x4){0.f, 0.f, 0.f, 0.f};
            f32x4 ab = (f32x4){0.f, 0.f, 0.f, 0.f};
#pragma unroll
            for (int ks = 0; ks < 4; ++ks) {
                const int sp = (kh << 8) + (ks << 5) + (lg << 3);
                const sh8 axh = *reinterpret_cast<const sh8*>(&xs_h[lr16][sp]);
                const sh8 axl = *reinterpret_cast<const sh8*>(&xs_l[lr16][sp]);
                aa = MFMA16(axh, whi[ks], aa);
                aa = MFMA16(axl, whi[ks], aa);
                aa = MFMA16(axh, wlo[ks], aa);
            }
#pragma unroll
            for (int ks = 4; ks < 8; ++ks) {
                const int sp = (kh << 8) + (ks << 5) + (lg << 3);
                const sh8 axh = *reinterpret_cast<const sh8*>(&xs_h[lr16][sp]);
                const sh8 axl = *reinterpret_cast<const sh8*>(&xs_l[lr16][sp]);
                ab = MFMA16(axh, whi[ks], ab);
                ab = MFMA16(axl, whi[ks], ab);
                ab = MFMA16(axh, wlo[ks], ab);
            }
            const f32x4 A = aa + ab;
#pragma unroll
            for (int r = 0; r < 4; ++r)
                psy[kh][(lg << 2) + r][18 * nt + lr16] = A[r];
        }
        __syncthreads();
    }
#pragma unroll
    for (int rr = 0; rr < 2; ++rr) {
        const int m = (w << 1) + rr;
        const float v = psy[0][m][18 * lg + lr16] + psy[1][m][18 * lg + lr16] + bias;
        const int s = (c << 6) + (3 << 4) + m + 1;
        Y[(s * BB + b) * NY + l] = v;
    }
}

// =============== fallback: round-4/5 monolithic (verified) ===============
__global__ __launch_bounds__(512, 2)
void lru_mono(const float* __restrict__ y0, const float* __restrict__ U,
              const float* __restrict__ lmr, const float* __restrict__ lmi,
              const float* __restrict__ Bmat, const float* __restrict__ Wy2x,
              const float* __restrict__ by2x, const float* __restrict__ Wx2y,
              const float* __restrict__ bx2y, float* __restrict__ Y)
{
    const int b    = blockIdx.x;
    const int tid  = threadIdx.x;
    const int w    = tid >> 6;
    const int l    = tid & 63;
    const int lr16 = l & 15;
    const int lg   = l >> 4;

    __shared__ unsigned short us_h[2][64][MUSP], us_l[2][64][MUSP];
    __shared__ unsigned short xs_h[2][KK][MXSP], xs_l[2][KK][MXSP];
    __shared__ float          bu[KK][MBUP];
    __shared__ float          psy[4][2][16][MPSP];
    __shared__ float          y0s[NY];

    sh8 frg[32];
    float lamr = 0.f, lami = 0.f, xr = 0.f, xi = 0.f;
    float biasE = 0.f;
    int   xwrd  = 0;

    if (tid < NH2) {
#pragma unroll
        for (int q = 0; q < 8; ++q) {
            sh8 vh, vl;
#pragma unroll
            for (int h2 = 0; h2 < 2; ++h2) {
                const int hrow = (w << 7) + (q << 4) + lr16;
                const int u0   = (h2 << 4) + (lg << 2);
                const float4 f4 = *reinterpret_cast<const float4*>(&Bmat[hrow * NU + u0]);
                sh4 th, tl;
                cvt4(f4, th, tl);
#pragma unroll
                for (int j = 0; j < 4; ++j) { vh[h2 * 4 + j] = th[j]; vl[h2 * 4 + j] = tl[j]; }
            }
            frg[q] = vh;
            frg[8 + q] = vl;
        }
        lamr = lmr[tid];
        lami = lmi[tid];
        const int q_ = tid & 15, blk = tid >> 4;
        xwrd = blk * 16 + ((q_ & 7) >> 1) * 4 + (q_ >> 3) * 2 + (q_ & 1);
    } else {
        const int j = w - 4, ntp = j >> 1, kh = j & 1;
#pragma unroll
        for (int ntt = 0; ntt < 2; ++ntt) {
            const int n = ((ntp << 1) + ntt) * 16 + lr16;
            const float* Wn = Wx2y + n * NH;
#pragma unroll
            for (int ks = 0; ks < 8; ++ks) {
                sh8 vh, vl;
#pragma unroll
                for (int h2 = 0; h2 < 2; ++h2) {
                    const int k0 = (kh << 8) + (ks << 5) + (h2 << 4) + (lg << 2);
                    const int p0 = k0 >> 1;
                    const float e[4] = { Wn[p0], Wn[p0 + 256], Wn[p0 + 1], Wn[p0 + 257] };
#pragma unroll
                    for (int j2 = 0; j2 < 4; ++j2) {
                        const unsigned short h = bfh(e[j2]);
                        vh[h2 * 4 + j2] = (short)h;
                        vl[h2 * 4 + j2] = (short)bfh(e[j2] - bf2f(h));
                    }
                }
                frg[ntt * 8 + ks] = vh;
                frg[16 + ntt * 8 + ks] = vl;
            }
        }
        biasE = bx2y[(j << 4) + lr16];
    }

    const float4* Ug = reinterpret_cast<const float4*>(U);
    {
        const int i = tid, t = i >> 3, g = i & 7;
        const float4 f = Ug[((t * BB + b) << 3) + g];
        const int pos = (g < 4) ? (g << 3) : (((g - 4) << 3) + 4);
        sh4 vh, vl;
        cvt4(f, vh, vl);
        *reinterpret_cast<sh4*>(&us_h[0][t][pos]) = vh;
        *reinterpret_cast<sh4*>(&us_l[0][t][pos]) = vl;
    }
    if (tid < NY) y0s[tid] = y0[b * NY + tid];
    __syncthreads();

    if (tid < NH2) {
        const float* wr = &Wy2x[tid * NY];
        const float* wi = &Wy2x[(NH2 + tid) * NY];
        float a0 = 0, a1 = 0, a2 = 0, a3 = 0;
        float c0 = 0, c1 = 0, c2 = 0, c3 = 0;
#pragma unroll
        for (int y = 0; y < NY; y += 4) {
            a0 += wr[y + 0] * y0s[y + 0];
            a1 += wr[y + 1] * y0s[y + 1];
            a2 += wr[y + 2] * y0s[y + 2];
            a3 += wr[y + 3] * y0s[y + 3];
            c0 += wi[y + 0] * y0s[y + 0];
            c1 += wi[y + 1] * y0s[y + 1];
            c2 += wi[y + 2] * y0s[y + 2];
            c3 += wi[y + 3] * y0s[y + 3];
        }
        xr = by2x[tid]       + (a0 + a1) + (a2 + a3);
        xi = by2x[NH2 + tid] + (c0 + c1) + (c2 + c3);
        xs_store(reinterpret_cast<unsigned*>(&xs_h[1][0][0]),
                 reinterpret_cast<unsigned*>(&xs_l[1][0][0]), xwrd, xr, xi);
    }
    __syncthreads();

    float4 pf0, pf1;

    for (int st = 0; st <= 32; ++st) {
        if (tid < NH2) {
            if (st < 32) {
                const int su = (st >> 2) & 1, t0 = (st & 3) << 4;
                const sh8 auh = *reinterpret_cast<const sh8*>(&us_h[su][t0 + lr16][lg << 3]);
                const sh8 aul = *reinterpret_cast<const sh8*>(&us_l[su][t0 + lr16][lg << 3]);
#pragma unroll
                for (int q = 0; q < 8; ++q) {
                    f32x4 acc = (f32x4){0.f, 0.f, 0.f, 0.f};
                    acc = MFMA16(auh, frg[q], acc);
                    acc = MFMA16(aul, frg[q], acc);
                    acc = MFMA16(auh, frg[8 + q], acc);
                    const int h = (w << 7) + (q << 4) + lr16;
#pragma unroll
                    for (int r = 0; r < 4; ++r) bu[(lg << 2) + r][h] = acc[r];
                }
            }
        } else {
            const int cc = st >> 2;
            if ((st & 3) == 0 && cc < 7 && st < 32) {
                const int i0 = tid - NH2, i1 = tid;
                pf0 = Ug[(((((cc + 1) << 6) + (i0 >> 3)) * BB + b) << 3) + (i0 & 7)];
                pf1 = Ug[(((((cc + 1) << 6) + (i1 >> 3)) * BB + b) << 3) + (i1 & 7)];
            }
            const int sx = (st + 1) & 1;
            const int j = w - 4, kh = j & 1;
            f32x4 a0a = (f32x4){0.f, 0.f, 0.f, 0.f};
            f32x4 a1a = (f32x4){0.f, 0.f, 0.f, 0.f};
#pragma unroll
            for (int ks = 0; ks < 8; ++ks) {
                const int sp = (kh << 8) + (ks << 5) + (lg << 3);
                const sh8 axh = *reinterpret_cast<const sh8*>(&xs_h[sx][lr16][sp]);
                const sh8 axl = *reinterpret_cast<const sh8*>(&xs_l[sx][lr16][sp]);
                a0a = MFMA16(axh, frg[ks], a0a);
                a0a = MFMA16(axl, frg[ks], a0a);
                a0a = MFMA16(axh, frg[16 + ks], a0a);
                a1a = MFMA16(axh, frg[8 + ks], a1a);
                a1a = MFMA16(axl, frg[8 + ks], a1a);
                a1a = MFMA16(axh, frg[24 + ks], a1a);
            }
#pragma unroll
            for (int r = 0; r < 4; ++r) {
                psy[j][0][(lg << 2) + r][lr16] = a0a[r];
                psy[j][1][(lg << 2) + r][lr16] = a1a[r];
            }
        }
        __syncthreads();

        if (tid < NH2) {
            if (st < 32) {
                const int sw = st & 1;
                unsigned* xh = reinterpret_cast<unsigned*>(&xs_h[sw][0][0]);
                unsigned* xl = reinterpret_cast<unsigned*>(&xs_l[sw][0][0]);
#pragma unroll
                for (int k = 0; k < KK; ++k) {
                    const float bur = bu[k][tid];
                    const float bui = bu[k][256 + tid];
                    const float nr = lamr * xr - lami * xi + bur;
                    const float ni = lami * xr + lamr * xi + bui;
                    xr = nr;
                    xi = ni;
                    xs_store(xh, xl, k * (MXSP / 2) + xwrd, xr, xi);
                }
            }
        } else {
            if ((st & 3) == 1 && (st >> 2) < 7) {
                const int ns = ((st >> 2) + 1) & 1;
#pragma unroll
                for (int v = 0; v < 2; ++v) {
                    const float4 f = v ? pf1 : pf0;
                    const int i = v ? tid : (tid - NH2);
                    const int t = i >> 3, g = i & 7;
                    const int pos = (g < 4) ? (g << 3) : (((g - 4) << 3) + 4);
                    sh4 vh, vl;
                    cvt4(f, vh, vl);
                    *reinterpret_cast<sh4*>(&us_h[ns][t][pos]) = vh;
                    *reinterpret_cast<sh4*>(&us_l[ns][t][pos]) = vl;
                }
            }
            const int j = w - 4;
            const int j0 = j & ~1;
#pragma unroll
            for (int r = 0; r < 4; ++r) {
                const int m = (lg << 2) + r;
                const float v = psy[j0][j & 1][m][lr16] + psy[j0 + 1][j & 1][m][lr16] + biasE;
                if (st == 0) {
                    if (m == 0) Y[b * NY + (j << 4) + lr16] = v;
                } else {
                    const int s = ((st - 1) << 4) + m + 1;
                    Y[(s * BB + b) * NY + (j << 4) + lr16] = v;
                }
            }
        }
        __syncthreads();
    }
}

extern "C" void kernel_launch(void* const* d_in, const int* in_sizes, int n_in,
                              void* d_out, int out_size, void* d_ws, size_t ws_size,
                              hipStream_t stream) {
    const float* y0   = (const float*)d_in[0];
    const float* U    = (const float*)d_in[1];
    const float* lmr  = (const float*)d_in[2];
    const float* lmi  = (const float*)d_in[3];
    const float* Bm   = (const float*)d_in[4];
    const float* Wy2x = (const float*)d_in[5];
    const float* by2x = (const float*)d_in[6];
    const float* Wx2y = (const float*)d_in[7];
    const float* bx2y = (const float*)d_in[8];
    float* Y = (float*)d_out;

    const size_t need = (size_t)256 * 8 * 512 * sizeof(float);   // 4.2 MB
    if (d_ws != nullptr && ws_size >= need) {
        float* wsX = (float*)d_ws;
        k_state<<<dim3(BB),   dim3(512), 0, stream>>>(y0, U, lmr, lmi, Bm, Wy2x, by2x, wsX);
        k_y0   <<<dim3(BB),   dim3(256), 0, stream>>>(Wx2y, bx2y, wsX, Y);
        k_main <<<dim3(2048), dim3(512), 0, stream>>>(U, lmr, lmi, Bm, Wx2y, bx2y, wsX, Y);
    } else {
        lru_mono<<<dim3(BB), dim3(512), 0, stream>>>(
            y0, U, lmr, lmi, Bm, Wy2x, by2x, Wx2y, bx2y, Y);
    }
}

// Round 9
// 217.055 us; speedup vs baseline: 1.4361x; 1.4361x over previous
//
#include <hip/hip_runtime.h>

// LRU recurrence — chunked scan, round-9.
//  k_state (256 blocks, 512 thr): producer/consumer. Waves 0-3: fp32 recurrence
//    (batch-loaded bu) + snapshots x_{64c} -> ws. Waves 4-7: NEXT superstep's
//    Bu-MFMA into double-buffered bu[2] + U staging. 1 barrier/superstep, 28 ss.
//  k_y0 (256 blocks): Y[0] from snapshot 0.
//  k_main (2048 blocks (b,c), 512 thr): Bu-MFMA -> fp32 recurrence from
//    snapshot -> Y-MFMA -> store. Round-8 verified structure; B and W operands
//    now single RNE-bf16 fragments (U, X stay hi/lo) -> ~100 VGPR, no spill,
//    2 blocks/CU.
//  Fallback lru_mono (verified r4/5) when ws too small.

constexpr int NY  = 64;
constexpr int NU  = 32;
constexpr int NH  = 512;
constexpr int NH2 = 256;
constexpr int BB  = 256;
constexpr int KK  = 16;

// k_state / mono pitches
constexpr int MUSP = 40;
constexpr int MXSP = 544;
constexpr int MBUP = 516;
constexpr int MPSP = 20;
// k_main pitches (round-8 verified)
constexpr int USP = 40;
constexpr int XSP = 520;
constexpr int BUP = 513;
constexpr int PSP = 74;

typedef __attribute__((ext_vector_type(4))) short sh4;
typedef __attribute__((ext_vector_type(8))) short sh8;
typedef __attribute__((ext_vector_type(4))) float f32x4;

#define MFMA16(a, b, c) __builtin_amdgcn_mfma_f32_16x16x32_bf16((a), (b), (c), 0, 0, 0)

static __device__ __forceinline__ unsigned short bfh(float x) {
    return (unsigned short)(__float_as_uint(x) >> 16);
}
static __device__ __forceinline__ float bf2f(unsigned short h) {
    return __uint_as_float(((unsigned)h) << 16);
}
static __device__ __forceinline__ void cvt4(const float4 f, sh4& vh, sh4& vl) {
    const float e[4] = { f.x, f.y, f.z, f.w };
#pragma unroll
    for (int j = 0; j < 4; ++j) {
        const unsigned short h = bfh(e[j]);
        vh[j] = (short)h;
        vl[j] = (short)bfh(e[j] - bf2f(h));
    }
}
static __device__ __forceinline__ unsigned cvtpk(float a, float b) {
    unsigned r;
    asm("v_cvt_pk_bf16_f32 %0, %1, %2" : "=v"(r) : "v"(a), "v"(b));
    return r;
}
static __device__ __forceinline__ sh8 pk8(const float* e) {   // 8 f32 -> 8 RNE bf16
    union { unsigned u[4]; sh8 s; } r;
    r.u[0] = cvtpk(e[0], e[1]);
    r.u[1] = cvtpk(e[2], e[3]);
    r.u[2] = cvtpk(e[4], e[5]);
    r.u[3] = cvtpk(e[6], e[7]);
    return r.s;
}
static __device__ __forceinline__ void xs_store(unsigned* xh, unsigned* xl, int idx,
                                                float xr, float xi) {
    const unsigned hp = cvtpk(xr, xi);
    const float rr = __uint_as_float(hp << 16);
    const float ri = __uint_as_float(hp & 0xffff0000u);
    xh[idx] = hp;
    xl[idx] = cvtpk(xr - rr, xi - ri);
}

// =============== k_state: producer/consumer snapshot pass ===============
__global__ __launch_bounds__(512, 2)
void k_state(const float* __restrict__ y0, const float* __restrict__ U,
             const float* __restrict__ lmr, const float* __restrict__ lmi,
             const float* __restrict__ Bmat, const float* __restrict__ Wy2x,
             const float* __restrict__ by2x, float* __restrict__ wsX)
{
    const int b = blockIdx.x, tid = threadIdx.x;
    const int w = tid >> 6, l = tid & 63, lr16 = l & 15, lg = l >> 4;

    __shared__ unsigned short us_h[2][64][MUSP], us_l[2][64][MUSP];   // 20.5 KB
    __shared__ float bu[2][KK][BUP];                                  // 65.7 KB
    __shared__ float y0s[NY];

    // producers (waves 4-7): B fragments, RNE bf16; wave pid owns h [pid*128,+128)
    sh8 bq[8];
    float lamr = 0.f, lami = 0.f, xr = 0.f, xi = 0.f;
    if (tid >= NH2) {
        const int pid = w - 4;
#pragma unroll
        for (int q = 0; q < 8; ++q) {
            float e8[8];
#pragma unroll
            for (int h2 = 0; h2 < 2; ++h2) {
                const int hrow = (pid << 7) + (q << 4) + lr16;
                const int u0   = (h2 << 4) + (lg << 2);
                const float4 f4 = *reinterpret_cast<const float4*>(&Bmat[hrow * NU + u0]);
                e8[h2 * 4 + 0] = f4.x; e8[h2 * 4 + 1] = f4.y;
                e8[h2 * 4 + 2] = f4.z; e8[h2 * 4 + 3] = f4.w;
            }
            bq[q] = pk8(e8);
        }
    } else {
        lamr = lmr[tid];
        lami = lmi[tid];
    }

    // stage U chunk 0 (hi/lo), all 512 threads
    const float4* Ug = reinterpret_cast<const float4*>(U);
    {
        const int i = tid, t = i >> 3, g = i & 7;
        const float4 f = Ug[((t * BB + b) << 3) + g];
        const int pos = (g < 4) ? (g << 3) : (((g - 4) << 3) + 4);
        sh4 vh, vl;
        cvt4(f, vh, vl);
        *reinterpret_cast<sh4*>(&us_h[0][t][pos]) = vh;
        *reinterpret_cast<sh4*>(&us_l[0][t][pos]) = vl;
    }
    if (tid < NY) y0s[tid] = y0[b * NY + tid];
    __syncthreads();

    if (tid < NH2) {
        // x0 = y0 @ Wy2x^T + by2x (fp32, verbatim verified)
        const float* wr = &Wy2x[tid * NY];
        const float* wi = &Wy2x[(NH2 + tid) * NY];
        float a0 = 0, a1 = 0, a2 = 0, a3 = 0;
        float c0 = 0, c1 = 0, c2 = 0, c3 = 0;
#pragma unroll
        for (int y = 0; y < NY; y += 4) {
            a0 += wr[y + 0] * y0s[y + 0];
            a1 += wr[y + 1] * y0s[y + 1];
            a2 += wr[y + 2] * y0s[y + 2];
            a3 += wr[y + 3] * y0s[y + 3];
            c0 += wi[y + 0] * y0s[y + 0];
            c1 += wi[y + 1] * y0s[y + 1];
            c2 += wi[y + 2] * y0s[y + 2];
            c3 += wi[y + 3] * y0s[y + 3];
        }
        xr = by2x[tid]       + (a0 + a1) + (a2 + a3);
        xi = by2x[NH2 + tid] + (c0 + c1) + (c2 + c3);
    } else {
        // prologue: Bu for ss=0 into bu[0] (reads us[0] rows 0..15)
        const int pid = w - 4;
        const sh8 auh = *reinterpret_cast<const sh8*>(&us_h[0][lr16][lg << 3]);
        const sh8 aul = *reinterpret_cast<const sh8*>(&us_l[0][lr16][lg << 3]);
#pragma unroll
        for (int q = 0; q < 8; ++q) {
            f32x4 acc = (f32x4){0.f, 0.f, 0.f, 0.f};
            acc = MFMA16(auh, bq[q], acc);
            acc = MFMA16(aul, bq[q], acc);
            const int h = (pid << 7) + (q << 4) + lr16;
#pragma unroll
            for (int r = 0; r < 4; ++r) bu[0][(lg << 2) + r][h] = acc[r];
        }
    }
    __syncthreads();

    float4 pf0, pf1;
    for (int ss = 0; ss < 28; ++ss) {
        if (tid < NH2) {
            // snapshot x_{16*ss} at chunk boundaries
            if ((ss & 3) == 0) {
                wsX[(b * 8 + (ss >> 2)) * 512 + tid]       = xr;
                wsX[(b * 8 + (ss >> 2)) * 512 + 256 + tid] = xi;
            }
            // recurrence for steps 16ss..16ss+15, batch-loaded bu[ss&1]
            const int cb = ss & 1;
            float bur[KK], bui[KK];
#pragma unroll
            for (int k = 0; k < KK; ++k) {
                bur[k] = bu[cb][k][tid];
                bui[k] = bu[cb][k][256 + tid];
            }
#pragma unroll
            for (int k = 0; k < KK; ++k) {
                const float nr = lamr * xr - lami * xi + bur[k];
                const float ni = lami * xr + lamr * xi + bui[k];
                xr = nr;
                xi = ni;
            }
        } else {
            const int cc = ss >> 2;
            if ((ss & 3) == 0 && cc < 6) {    // issue prefetch for chunk cc+1
                const int i0 = tid - NH2, i1 = tid;
                pf0 = Ug[(((((cc + 1) << 6) + (i0 >> 3)) * BB + b) << 3) + (i0 & 7)];
                pf1 = Ug[(((((cc + 1) << 6) + (i1 >> 3)) * BB + b) << 3) + (i1 & 7)];
            }
            if ((ss & 3) == 1 && cc < 6) {    // commit chunk cc+1 -> us[(cc+1)&1]
                const int ns = (cc + 1) & 1;
#pragma unroll
                for (int v = 0; v < 2; ++v) {
                    const float4 f = v ? pf1 : pf0;
                    const int i = v ? tid : (tid - NH2);
                    const int t = i >> 3, g = i & 7;
                    const int pos = (g < 4) ? (g << 3) : (((g - 4) << 3) + 4);
                    sh4 vh, vl;
                    cvt4(f, vh, vl);
                    *reinterpret_cast<sh4*>(&us_h[ns][t][pos]) = vh;
                    *reinterpret_cast<sh4*>(&us_l[ns][t][pos]) = vl;
                }
            }
            if (ss < 27) {   // Bu for superstep ss+1 into bu[(ss+1)&1]
                const int pid = w - 4;
                const int s1 = ss + 1, ub = (s1 >> 2) & 1, t0 = (s1 & 3) << 4;
                const sh8 auh = *reinterpret_cast<const sh8*>(&us_h[ub][t0 + lr16][lg << 3]);
                const sh8 aul = *reinterpret_cast<const sh8*>(&us_l[ub][t0 + lr16][lg << 3]);
#pragma unroll
                for (int q = 0; q < 8; ++q) {
                    f32x4 acc = (f32x4){0.f, 0.f, 0.f, 0.f};
                    acc = MFMA16(auh, bq[q], acc);
                    acc = MFMA16(aul, bq[q], acc);
                    const int h = (pid << 7) + (q << 4) + lr16;
#pragma unroll
                    for (int r = 0; r < 4; ++r) bu[s1 & 1][(lg << 2) + r][h] = acc[r];
                }
            }
        }
        __syncthreads();
    }
    if (tid < NH2) {   // snapshot slot 7 = x_448
        wsX[(b * 8 + 7) * 512 + tid]       = xr;
        wsX[(b * 8 + 7) * 512 + 256 + tid] = xi;
    }
}

// =============== k_y0: Y[0] from snapshot slot 0 ===============
__global__ __launch_bounds__(256)
void k_y0(const float* __restrict__ Wx2y, const float* __restrict__ bx2y,
          const float* __restrict__ wsX, float* __restrict__ Y)
{
    const int b = blockIdx.x, tid = threadIdx.x;
    __shared__ float x0s[NH];
    __shared__ float ps0[4][80];

    x0s[tid]       = wsX[(b * 8) * 512 + tid];
    x0s[256 + tid] = wsX[(b * 8) * 512 + 256 + tid];
    __syncthreads();

    const int n = tid & 63, kq = tid >> 6;
    const float* Wn = Wx2y + n * NH + (kq << 7);
    const float* xq = x0s + (kq << 7);
    float a0 = 0, a1 = 0, a2 = 0, a3 = 0;
#pragma unroll
    for (int h = 0; h < 128; h += 4) {
        a0 += Wn[h + 0] * xq[h + 0];
        a1 += Wn[h + 1] * xq[h + 1];
        a2 += Wn[h + 2] * xq[h + 2];
        a3 += Wn[h + 3] * xq[h + 3];
    }
    ps0[kq][n] = (a0 + a1) + (a2 + a3);
    __syncthreads();
    if (tid < NY)
        Y[b * NY + tid] = ps0[0][tid] + ps0[1][tid] + ps0[2][tid] + ps0[3][tid] + bx2y[tid];
}

// =============== k_main: chunk-parallel pipeline (r8-verified, slim frags) ===============
__global__ __launch_bounds__(512, 4)
void k_main(const float* __restrict__ U,
            const float* __restrict__ lmr, const float* __restrict__ lmi,
            const float* __restrict__ Bmat, const float* __restrict__ Wx2y,
            const float* __restrict__ bx2y, const float* __restrict__ wsX,
            float* __restrict__ Y)
{
    const int bc = blockIdx.x;
    const int b = bc >> 3, c = bc & 7;
    const int tid = threadIdx.x;
    const int w = tid >> 6, l = tid & 63, lr16 = l & 15, lg = l >> 4;

    __shared__ unsigned short us_h[KK][USP], us_l[KK][USP];
    __shared__ unsigned short xs_h[KK][XSP], xs_l[KK][XSP];
    __shared__ float bu[KK][BUP];
    __shared__ float psy[2][KK][PSP];

    // Bu B-frags: RNE bf16 single; wave w owns hidden [w*64, w*64+64)
    sh8 bq[4];
#pragma unroll
    for (int q = 0; q < 4; ++q) {
        float e8[8];
#pragma unroll
        for (int h2 = 0; h2 < 2; ++h2) {
            const int hrow = (w << 6) + (q << 4) + lr16;
            const int u0   = (h2 << 4) + (lg << 2);
            const float4 f4 = *reinterpret_cast<const float4*>(&Bmat[hrow * NU + u0]);
            e8[h2 * 4 + 0] = f4.x; e8[h2 * 4 + 1] = f4.y;
            e8[h2 * 4 + 2] = f4.z; e8[h2 * 4 + 3] = f4.w;
        }
        bq[q] = pk8(e8);
    }

    // W-frags: RNE bf16 single; wave -> (nt = w>>1, kh = w&1), 8 k-slices
    const int nt = w >> 1, kh = w & 1;
    sh8 whi[8];
    {
        const float* Wn = Wx2y + ((nt << 4) + lr16) * NH;
#pragma unroll
        for (int ks = 0; ks < 8; ++ks) {
            float e8[8];
#pragma unroll
            for (int h2 = 0; h2 < 2; ++h2) {
                const int k0 = (kh << 8) + (ks << 5) + (h2 << 4) + (lg << 2);
                const int p0 = k0 >> 1;
                e8[h2 * 4 + 0] = Wn[p0];
                e8[h2 * 4 + 1] = Wn[p0 + 256];
                e8[h2 * 4 + 2] = Wn[p0 + 1];
                e8[h2 * 4 + 3] = Wn[p0 + 257];
            }
            whi[ks] = pk8(e8);
        }
    }
    const float bias = bx2y[l];

    float lamr = 0.f, lami = 0.f, xr = 0.f, xi = 0.f;
    int xwrd = 0;
    if (tid < NH2) {
        lamr = lmr[tid];
        lami = lmi[tid];
        xr = wsX[(b * 8 + c) * 512 + tid];         // snapshot x_{64c}
        xi = wsX[(b * 8 + c) * 512 + 256 + tid];
        const int q_ = tid & 15, blk = tid >> 4;
        xwrd = blk * 16 + ((q_ & 7) >> 1) * 4 + (q_ >> 3) * 2 + (q_ & 1);
    }

    const float4* Ug = reinterpret_cast<const float4*>(U);
    float4 pf;
    if (tid < 128) {
        const int tg = (c << 6) + (tid >> 3), g = tid & 7;
        pf = Ug[(tg * BB + b) * 8 + g];
    }

    for (int ss = 0; ss < 4; ++ss) {
        if (tid < 128) {
            const float4 cur = pf;
            if (ss < 3) {
                const int tg = (c << 6) + ((ss + 1) << 4) + (tid >> 3), g = tid & 7;
                pf = Ug[(tg * BB + b) * 8 + g];
            }
            const int t = tid >> 3, g = tid & 7;
            const int pos = (g < 4) ? (g << 3) : (((g - 4) << 3) + 4);
            sh4 vh, vl;
            cvt4(cur, vh, vl);
            *reinterpret_cast<sh4*>(&us_h[t][pos]) = vh;
            *reinterpret_cast<sh4*>(&us_l[t][pos]) = vl;
        }
        if (ss > 0) {
#pragma unroll
            for (int rr = 0; rr < 2; ++rr) {
                const int m = (w << 1) + rr;
                const float v = psy[0][m][18 * lg + lr16] + psy[1][m][18 * lg + lr16] + bias;
                const int s = (c << 6) + ((ss - 1) << 4) + m + 1;
                Y[(s * BB + b) * NY + l] = v;
            }
        }
        __syncthreads();
        {
            const sh8 auh = *reinterpret_cast<const sh8*>(&us_h[lr16][lg << 3]);
            const sh8 aul = *reinterpret_cast<const sh8*>(&us_l[lr16][lg << 3]);
#pragma unroll
            for (int q = 0; q < 4; ++q) {
                f32x4 acc = (f32x4){0.f, 0.f, 0.f, 0.f};
                acc = MFMA16(auh, bq[q], acc);
                acc = MFMA16(aul, bq[q], acc);
                const int h = (w << 6) + (q << 4) + lr16;
#pragma unroll
                for (int r = 0; r < 4; ++r) bu[(lg << 2) + r][h] = acc[r];
            }
        }
        __syncthreads();
        if (tid < NH2) {
            unsigned* xh = reinterpret_cast<unsigned*>(&xs_h[0][0]);
            unsigned* xl = reinterpret_cast<unsigned*>(&xs_l[0][0]);
#pragma unroll
            for (int k = 0; k < KK; ++k) {
                const float bur = bu[k][tid];
                const float bui = bu[k][256 + tid];
                const float nr = lamr * xr - lami * xi + bur;
                const float ni = lami * xr + lamr * xi + bui;
                xr = nr;
                xi = ni;
                xs_store(xh, xl, k * (XSP / 2) + xwrd, xr, xi);
            }
        }
        __syncthreads();
        {
            f32x4 aa = (f32x4){0.f, 0.f, 0.f, 0.f};
            f32x4 ab = (f32x4){0.f, 0.f, 0.f, 0.f};
#pragma unroll
            for (int ks = 0; ks < 4; ++ks) {
                const int sp = (kh << 8) + (ks << 5) + (lg << 3);
                const sh8 axh = *reinterpret_cast<const sh8*>(&xs_h[lr16][sp]);
                const sh8 axl = *reinterpret_cast<const sh8*>(&xs_l[lr16][sp]);
                aa = MFMA16(axh, whi[ks], aa);
                aa = MFMA16(axl, whi[ks], aa);
            }
#pragma unroll
            for (int ks = 4; ks < 8; ++ks) {
                const int sp = (kh << 8) + (ks << 5) + (lg << 3);
                const sh8 axh = *reinterpret_cast<const sh8*>(&xs_h[lr16][sp]);
                const sh8 axl = *reinterpret_cast<const sh8*>(&xs_l[lr16][sp]);
                ab = MFMA16(axh, whi[ks], ab);
                ab = MFMA16(axl, whi[ks], ab);
            }
            const f32x4 A = aa + ab;
#pragma unroll
            for (int r = 0; r < 4; ++r)
                psy[kh][(lg << 2) + r][18 * nt + lr16] = A[r];
        }
        __syncthreads();
    }
#pragma unroll
    for (int rr = 0; rr < 2; ++rr) {
        const int m = (w << 1) + rr;
        const float v = psy[0][m][18 * lg + lr16] + psy[1][m][18 * lg + lr16] + bias;
        const int s = (c << 6) + (3 << 4) + m + 1;
        Y[(s * BB + b) * NY + l] = v;
    }
}

// =============== fallback: round-4/5 monolithic (verified) ===============
__global__ __launch_bounds__(512, 2)
void lru_mono(const float* __restrict__ y0, const float* __restrict__ U,
              const float* __restrict__ lmr, const float* __restrict__ lmi,
              const float* __restrict__ Bmat, const float* __restrict__ Wy2x,
              const float* __restrict__ by2x, const float* __restrict__ Wx2y,
              const float* __restrict__ bx2y, float* __restrict__ Y)
{
    const int b    = blockIdx.x;
    const int tid  = threadIdx.x;
    const int w    = tid >> 6;
    const int l    = tid & 63;
    const int lr16 = l & 15;
    const int lg   = l >> 4;

    __shared__ unsigned short us_h[2][64][MUSP], us_l[2][64][MUSP];
    __shared__ unsigned short xs_h[2][KK][MXSP], xs_l[2][KK][MXSP];
    __shared__ float          bu[KK][MBUP];
    __shared__ float          psy[4][2][16][MPSP];
    __shared__ float          y0s[NY];

    sh8 frg[32];
    float lamr = 0.f, lami = 0.f, xr = 0.f, xi = 0.f;
    float biasE = 0.f;
    int   xwrd  = 0;

    if (tid < NH2) {
#pragma unroll
        for (int q = 0; q < 8; ++q) {
            sh8 vh, vl;
#pragma unroll
            for (int h2 = 0; h2 < 2; ++h2) {
                const int hrow = (w << 7) + (q << 4) + lr16;
                const int u0   = (h2 << 4) + (lg << 2);
                const float4 f4 = *reinterpret_cast<const float4*>(&Bmat[hrow * NU + u0]);
                sh4 th, tl;
                cvt4(f4, th, tl);
#pragma unroll
                for (int j = 0; j < 4; ++j) { vh[h2 * 4 + j] = th[j]; vl[h2 * 4 + j] = tl[j]; }
            }
            frg[q] = vh;
            frg[8 + q] = vl;
        }
        lamr = lmr[tid];
        lami = lmi[tid];
        const int q_ = tid & 15, blk = tid >> 4;
        xwrd = blk * 16 + ((q_ & 7) >> 1) * 4 + (q_ >> 3) * 2 + (q_ & 1);
    } else {
        const int j = w - 4, ntp = j >> 1, kh = j & 1;
#pragma unroll
        for (int ntt = 0; ntt < 2; ++ntt) {
            const int n = ((ntp << 1) + ntt) * 16 + lr16;
            const float* Wn = Wx2y + n * NH;
#pragma unroll
            for (int ks = 0; ks < 8; ++ks) {
                sh8 vh, vl;
#pragma unroll
                for (int h2 = 0; h2 < 2; ++h2) {
                    const int k0 = (kh << 8) + (ks << 5) + (h2 << 4) + (lg << 2);
                    const int p0 = k0 >> 1;
                    const float e[4] = { Wn[p0], Wn[p0 + 256], Wn[p0 + 1], Wn[p0 + 257] };
#pragma unroll
                    for (int j2 = 0; j2 < 4; ++j2) {
                        const unsigned short h = bfh(e[j2]);
                        vh[h2 * 4 + j2] = (short)h;
                        vl[h2 * 4 + j2] = (short)bfh(e[j2] - bf2f(h));
                    }
                }
                frg[ntt * 8 + ks] = vh;
                frg[16 + ntt * 8 + ks] = vl;
            }
        }
        biasE = bx2y[(j << 4) + lr16];
    }

    const float4* Ug = reinterpret_cast<const float4*>(U);
    {
        const int i = tid, t = i >> 3, g = i & 7;
        const float4 f = Ug[((t * BB + b) << 3) + g];
        const int pos = (g < 4) ? (g << 3) : (((g - 4) << 3) + 4);
        sh4 vh, vl;
        cvt4(f, vh, vl);
        *reinterpret_cast<sh4*>(&us_h[0][t][pos]) = vh;
        *reinterpret_cast<sh4*>(&us_l[0][t][pos]) = vl;
    }
    if (tid < NY) y0s[tid] = y0[b * NY + tid];
    __syncthreads();

    if (tid < NH2) {
        const float* wr = &Wy2x[tid * NY];
        const float* wi = &Wy2x[(NH2 + tid) * NY];
        float a0 = 0, a1 = 0, a2 = 0, a3 = 0;
        float c0 = 0, c1 = 0, c2 = 0, c3 = 0;
#pragma unroll
        for (int y = 0; y < NY; y += 4) {
            a0 += wr[y + 0] * y0s[y + 0];
            a1 += wr[y + 1] * y0s[y + 1];
            a2 += wr[y + 2] * y0s[y + 2];
            a3 += wr[y + 3] * y0s[y + 3];
            c0 += wi[y + 0] * y0s[y + 0];
            c1 += wi[y + 1] * y0s[y + 1];
            c2 += wi[y + 2] * y0s[y + 2];
            c3 += wi[y + 3] * y0s[y + 3];
        }
        xr = by2x[tid]       + (a0 + a1) + (a2 + a3);
        xi = by2x[NH2 + tid] + (c0 + c1) + (c2 + c3);
        xs_store(reinterpret_cast<unsigned*>(&xs_h[1][0][0]),
                 reinterpret_cast<unsigned*>(&xs_l[1][0][0]), xwrd, xr, xi);
    }
    __syncthreads();

    float4 pf0, pf1;

    for (int st = 0; st <= 32; ++st) {
        if (tid < NH2) {
            if (st < 32) {
                const int su = (st >> 2) & 1, t0 = (st & 3) << 4;
                const sh8 auh = *reinterpret_cast<const sh8*>(&us_h[su][t0 + lr16][lg << 3]);
                const sh8 aul = *reinterpret_cast<const sh8*>(&us_l[su][t0 + lr16][lg << 3]);
#pragma unroll
                for (int q = 0; q < 8; ++q) {
                    f32x4 acc = (f32x4){0.f, 0.f, 0.f, 0.f};
                    acc = MFMA16(auh, frg[q], acc);
                    acc = MFMA16(aul, frg[q], acc);
                    acc = MFMA16(auh, frg[8 + q], acc);
                    const int h = (w << 7) + (q << 4) + lr16;
#pragma unroll
                    for (int r = 0; r < 4; ++r) bu[(lg << 2) + r][h] = acc[r];
                }
            }
        } else {
            const int cc = st >> 2;
            if ((st & 3) == 0 && cc < 7 && st < 32) {
                const int i0 = tid - NH2, i1 = tid;
                pf0 = Ug[(((((cc + 1) << 6) + (i0 >> 3)) * BB + b) << 3) + (i0 & 7)];
                pf1 = Ug[(((((cc + 1) << 6) + (i1 >> 3)) * BB + b) << 3) + (i1 & 7)];
            }
            const int sx = (st + 1) & 1;
            const int j = w - 4, kh = j & 1;
            f32x4 a0a = (f32x4){0.f, 0.f, 0.f, 0.f};
            f32x4 a1a = (f32x4){0.f, 0.f, 0.f, 0.f};
#pragma unroll
            for (int ks = 0; ks < 8; ++ks) {
                const int sp = (kh << 8) + (ks << 5) + (lg << 3);
                const sh8 axh = *reinterpret_cast<const sh8*>(&xs_h[sx][lr16][sp]);
                const sh8 axl = *reinterpret_cast<const sh8*>(&xs_l[sx][lr16][sp]);
                a0a = MFMA16(axh, frg[ks], a0a);
                a0a = MFMA16(axl, frg[ks], a0a);
                a0a = MFMA16(axh, frg[16 + ks], a0a);
                a1a = MFMA16(axh, frg[8 + ks], a1a);
                a1a = MFMA16(axl, frg[8 + ks], a1a);
                a1a = MFMA16(axh, frg[24 + ks], a1a);
            }
#pragma unroll
            for (int r = 0; r < 4; ++r) {
                psy[j][0][(lg << 2) + r][lr16] = a0a[r];
                psy[j][1][(lg << 2) + r][lr16] = a1a[r];
            }
        }
        __syncthreads();

        if (tid < NH2) {
            if (st < 32) {
                const int sw = st & 1;
                unsigned* xh = reinterpret_cast<unsigned*>(&xs_h[sw][0][0]);
                unsigned* xl = reinterpret_cast<unsigned*>(&xs_l[sw][0][0]);
#pragma unroll
                for (int k = 0; k < KK; ++k) {
                    const float bur = bu[k][tid];
                    const float bui = bu[k][256 + tid];
                    const float nr = lamr * xr - lami * xi + bur;
                    const float ni = lami * xr + lamr * xi + bui;
                    xr = nr;
                    xi = ni;
                    xs_store(xh, xl, k * (MXSP / 2) + xwrd, xr, xi);
                }
            }
        } else {
            if ((st & 3) == 1 && (st >> 2) < 7) {
                const int ns = ((st >> 2) + 1) & 1;
#pragma unroll
                for (int v = 0; v < 2; ++v) {
                    const float4 f = v ? pf1 : pf0;
                    const int i = v ? tid : (tid - NH2);
                    const int t = i >> 3, g = i & 7;
                    const int pos = (g < 4) ? (g << 3) : (((g - 4) << 3) + 4);
                    sh4 vh, vl;
                    cvt4(f, vh, vl);
                    *reinterpret_cast<sh4*>(&us_h[ns][t][pos]) = vh;
                    *reinterpret_cast<sh4*>(&us_l[ns][t][pos]) = vl;
                }
            }
            const int j = w - 4;
            const int j0 = j & ~1;
#pragma unroll
            for (int r = 0; r < 4; ++r) {
                const int m = (lg << 2) + r;
                const float v = psy[j0][j & 1][m][lr16] + psy[j0 + 1][j & 1][m][lr16] + biasE;
                if (st == 0) {
                    if (m == 0) Y[b * NY + (j << 4) + lr16] = v;
                } else {
                    const int s = ((st - 1) << 4) + m + 1;
                    Y[(s * BB + b) * NY + (j << 4) + lr16] = v;
                }
            }
        }
        __syncthreads();
    }
}

extern "C" void kernel_launch(void* const* d_in, const int* in_sizes, int n_in,
                              void* d_out, int out_size, void* d_ws, size_t ws_size,
                              hipStream_t stream) {
    const float* y0   = (const float*)d_in[0];
    const float* U    = (const float*)d_in[1];
    const float* lmr  = (const float*)d_in[2];
    const float* lmi  = (const float*)d_in[3];
    const float* Bm   = (const float*)d_in[4];
    const float* Wy2x = (const float*)d_in[5];
    const float* by2x = (const float*)d_in[6];
    const float* Wx2y = (const float*)d_in[7];
    const float* bx2y = (const float*)d_in[8];
    float* Y = (float*)d_out;

    const size_t need = (size_t)256 * 8 * 512 * sizeof(float);   // 4.2 MB
    if (d_ws != nullptr && ws_size >= need) {
        float* wsX = (float*)d_ws;
        k_state<<<dim3(BB),   dim3(512), 0, stream>>>(y0, U, lmr, lmi, Bm, Wy2x, by2x, wsX);
        k_y0   <<<dim3(BB),   dim3(256), 0, stream>>>(Wx2y, bx2y, wsX, Y);
        k_main <<<dim3(2048), dim3(512), 0, stream>>>(U, lmr, lmi, Bm, Wx2y, bx2y, wsX, Y);
    } else {
        lru_mono<<<dim3(BB), dim3(512), 0, stream>>>(
            y0, U, lmr, lmi, Bm, Wy2x, by2x, Wx2y, bx2y, Y);
    }
}